// Round 11
// baseline (286.007 us; speedup 1.0000x reference)
//
#include <hip/hip_runtime.h>
#include <stdint.h>

#define GLOBAL_AS __attribute__((address_space(1)))
#define LDS_AS    __attribute__((address_space(3)))

typedef int   v4i  __attribute__((ext_vector_type(4)));
typedef int   v8i  __attribute__((ext_vector_type(8)));
typedef float v16f __attribute__((ext_vector_type(16)));

__device__ __forceinline__ void gload_lds16(const void* g, void* l) {
    __builtin_amdgcn_global_load_lds((GLOBAL_AS uint32_t*)g, (LDS_AS uint32_t*)l, 16, 0, 0);
}

// fp4 e2m1 encodings: {0,1,2,3} -> {0x0,0x2,0x4,0x5}; {-3,-1,1,3} -> {0xD,0xA,0x2,0x5}
//   act   nibble = (0x5420 >> (q*4)) & 0xF
//   wght  nibble = (0x52AD >> (q*4)) & 0xF   (q = 0..3 maps to -3,-1,1,3)

// ---------------- kernel 1 (fused): weight-max (blocks 0..47) + act quantize -> fp4 ----------
__global__ void k_xq_wmax(const float* __restrict__ x, const float* __restrict__ w,
                          int8_t* __restrict__ xqp, unsigned* __restrict__ maxbits) {
    const int bid = blockIdx.x;
    if (bid < 48) {
        int t = bid * 256 + threadIdx.x;
        const float4* w4 = (const float4*)w;
        float m = 0.f;
        for (int i = t; i < 147456; i += 12288) {
            float4 v = w4[i];
            m = fmaxf(m, fmaxf(fmaxf(fabsf(tanhf(v.x)), fabsf(tanhf(v.y))),
                               fmaxf(fabsf(tanhf(v.z)), fabsf(tanhf(v.w)))));
        }
#pragma unroll
        for (int off = 32; off > 0; off >>= 1)
            m = fmaxf(m, __shfl_xor(m, off, 64));
        if ((threadIdx.x & 63) == 0) atomicMax(maxbits, __float_as_uint(m));
        return;
    }
    int t = (bid - 48) * 256 + threadIdx.x;   // 32*58*58*8 threads, 16 bytes (32 ch) each
    int g  = t & 7;
    int p  = t >> 3;
    int xp = p % 58;
    int q  = p / 58;
    int yp = q % 58;
    int n  = q / 58;
    int4 r;
    if (yp == 0 || yp == 57 || xp == 0 || xp == 57) {
        r = make_int4(0, 0, 0, 0);
    } else {
        const float4* px = (const float4*)(x + (((long)((n * 56 + (yp - 1)) * 56 + (xp - 1))) << 8) + g * 32);
        int wds[4];
#pragma unroll
        for (int jj = 0; jj < 4; ++jj) {
            float4 v0 = px[jj * 2];
            float4 v1 = px[jj * 2 + 1];
            int q0 = (int)rintf(fminf(fmaxf(v0.x, 0.f), 1.f) * 3.f);
            int q1 = (int)rintf(fminf(fmaxf(v0.y, 0.f), 1.f) * 3.f);
            int q2 = (int)rintf(fminf(fmaxf(v0.z, 0.f), 1.f) * 3.f);
            int q3 = (int)rintf(fminf(fmaxf(v0.w, 0.f), 1.f) * 3.f);
            int q4 = (int)rintf(fminf(fmaxf(v1.x, 0.f), 1.f) * 3.f);
            int q5 = (int)rintf(fminf(fmaxf(v1.y, 0.f), 1.f) * 3.f);
            int q6 = (int)rintf(fminf(fmaxf(v1.z, 0.f), 1.f) * 3.f);
            int q7 = (int)rintf(fminf(fmaxf(v1.w, 0.f), 1.f) * 3.f);
            wds[jj] = ((0x5420 >> (q0 << 2)) & 0xF)        | (((0x5420 >> (q1 << 2)) & 0xF) << 4)
                    | (((0x5420 >> (q2 << 2)) & 0xF) << 8) | (((0x5420 >> (q3 << 2)) & 0xF) << 12)
                    | (((0x5420 >> (q4 << 2)) & 0xF) << 16)| (((0x5420 >> (q5 << 2)) & 0xF) << 20)
                    | (((0x5420 >> (q6 << 2)) & 0xF) << 24)| (((0x5420 >> (q7 << 2)) & 0xF) << 28);
        }
        r = make_int4(wds[0], wds[1], wds[2], wds[3]);
    }
    *(int4*)(xqp + ((long)t << 4)) = r;
}

// ---------------- kernel 2: quantize weights -> fp4 {-3,-1,1,3}, layout [co][tap*128+ci/2] ---
__global__ void k_wq(const float* __restrict__ w, const unsigned* __restrict__ maxbits,
                     int8_t* __restrict__ wqt) {
    int t = blockIdx.x * 256 + threadIdx.x;   // 18432 threads
    int co = t & 255;
    int kblk = t >> 8;                        // 0..71, 32 k-values each
    float inv = 0.5f / __uint_as_float(*maxbits);
    uint8_t b[16];
#pragma unroll
    for (int j = 0; j < 16; ++j) {
        float t0 = tanhf(w[(long)(kblk * 32 + 2 * j) * 256 + co]);     // HWIO [k][co]
        float t1 = tanhf(w[(long)(kblk * 32 + 2 * j + 1) * 256 + co]);
        int q0 = (int)rintf((t0 * inv + 0.5f) * 3.0f);                 // 0..3, half-even
        int q1 = (int)rintf((t1 * inv + 0.5f) * 3.0f);
        b[j] = (uint8_t)(((0x52AD >> (q0 << 2)) & 0xF) | (((0x52AD >> (q1 << 2)) & 0xF) << 4));
    }
    *(int4*)(wqt + (long)co * 1152 + kblk * 16) = *(int4*)b;
}

// ---------------- kernel 3: barrier-free implicit-GEMM conv, MX-fp4 MFMA 32x32x64 -----------
// A-window staged to 32KB LDS once; B global(L2)->regs, depth-1 double-buffer (sets bA/bC).
// Round-10 post-mortem: with no fences + full unroll the scheduler hoisted B-loads across all
// 9 taps -> VGPR hit the 256 cap (occupancy 1 wave/SIMD, 9.7%), 53MB residual spill writes.
// Fix: sched_barrier(0) after each tap's MFMA cluster bounds the hoisting window to one tap
// (live set ~160 VGPR -> 3 waves/SIMD) while keeping the depth-1 prefetch overlap.
__global__ __launch_bounds__(256) void k_conv(const int8_t* __restrict__ xqp,
                                              const int8_t* __restrict__ wqt,
                                              float* __restrict__ out) {
    __shared__ int8_t sX[256 * 128];   // 32 KB, staged once

    const int tid  = threadIdx.x;
    const int wv   = tid >> 6;
    const int lane = tid & 63;
    const int orig = blockIdx.x;                   // 1600 blocks, %8==0 -> bijective swizzle
    const int work = (orig & 7) * 200 + (orig >> 3);
    const int coBase = (work & 1) << 7;
    const int wt   = work >> 1;                    // 0..799
    const int n    = wt / 25;
    const int t    = wt - n * 25;

    const int m0 = t * 128;                        // local row base within image n
    const int y0 = m0 / 56;
    const int x0 = m0 - y0 * 56;
    const long pixBase = ((long)(n * 58 + y0)) * 58 + x0;  // padded pixel of tap(0,0), row 0

    // ---- stage A window: 256 pixels x 128B, chunk-swizzled (g = lp ^ (p&7)), once ----
    {
        const int lr = lane >> 3;
        const int lp = lane & 7;
#pragma unroll
        for (int j = 0; j < 8; ++j) {
            int p = wv * 8 + j * 32 + lr;          // 0..255
            int g = lp ^ (p & 7);
            long pg = pixBase + p;
            if (pg > 107647) pg = 107647;          // clamp inside xqp (32*58*58 pixels)
            gload_lds16(xqp + (pg << 7) + g * 16, &sX[(wv * 8 + j * 32) * 128]);
        }
    }

    const int wm  = (wv & 1) * 64;
    const int wn  = (wv >> 1) * 64;
    const int l31 = lane & 31;
    const int hi  = lane >> 5;
    const int h16 = hi << 4;

    // B row base pointers (per-lane); tap/kk offsets are immediates
    const int8_t* pB0 = wqt + (long)(coBase + wn + l31) * 1152 + h16;
    const int8_t* pB1 = pB0 + 32 * 1152;

    // per-thread A-row pixel offsets (relative to pixBase); pad rows clamp to m=3135
    int mL0 = m0 + wm + l31;      if (mL0 > 3135) mL0 = 3135;
    int mL1 = m0 + wm + 32 + l31; if (mL1 > 3135) mL1 = 3135;
    const int yR0 = mL0 / 56, xR0 = mL0 - yR0 * 56;
    const int yR1 = mL1 / 56, xR1 = mL1 - yR1 * 56;
    const int po0 = (yR0 - y0) * 58 + (xR0 - x0);   // <= 133
    const int po1 = (yR1 - y0) * 58 + (xR1 - x0);

    v16f acc00 = {0,0,0,0,0,0,0,0,0,0,0,0,0,0,0,0};
    v16f acc01 = {0,0,0,0,0,0,0,0,0,0,0,0,0,0,0,0};
    v16f acc10 = {0,0,0,0,0,0,0,0,0,0,0,0,0,0,0,0};
    v16f acc11 = {0,0,0,0,0,0,0,0,0,0,0,0,0,0,0,0};

    // B double-buffer: two named 8-fragment sets (no arrays anywhere)
    v4i bA_0, bA_1, bA_2, bA_3, bA_4, bA_5, bA_6, bA_7;
    v4i bC_0, bC_1, bC_2, bC_3, bC_4, bC_5, bC_6, bC_7;

    const int SC = 0x7F7F7F7F;                      // e8m0 127 -> scale 1.0

#define LOADSET(S, IT)                                                                     \
    {                                                                                      \
        const int8_t* p0 = pB0 + (IT) * 128;                                               \
        const int8_t* p1 = pB1 + (IT) * 128;                                               \
        S##_0 = *(const v4i*)(p0);      S##_1 = *(const v4i*)(p0 + 32);                    \
        S##_2 = *(const v4i*)(p0 + 64); S##_3 = *(const v4i*)(p0 + 96);                    \
        S##_4 = *(const v4i*)(p1);      S##_5 = *(const v4i*)(p1 + 32);                    \
        S##_6 = *(const v4i*)(p1 + 64); S##_7 = *(const v4i*)(p1 + 96);                    \
    }

#define MFMA_KK(KK, B0K, B1K)                                                              \
    {                                                                                      \
        const int kc = (KK) * 32 + h16;                                                    \
        v4i a0 = *(const v4i*)(a0b + (kc ^ xx0));                                          \
        v4i a1 = *(const v4i*)(a1b + (kc ^ xx1));                                          \
        v8i A0 = {a0[0], a0[1], a0[2], a0[3], 0, 0, 0, 0};                                 \
        v8i A1 = {a1[0], a1[1], a1[2], a1[3], 0, 0, 0, 0};                                 \
        v8i B0 = {B0K[0], B0K[1], B0K[2], B0K[3], 0, 0, 0, 0};                             \
        v8i B1 = {B1K[0], B1K[1], B1K[2], B1K[3], 0, 0, 0, 0};                             \
        acc00 = __builtin_amdgcn_mfma_scale_f32_32x32x64_f8f6f4(A0, B0, acc00, 4, 4, 0, SC, 0, SC); \
        acc01 = __builtin_amdgcn_mfma_scale_f32_32x32x64_f8f6f4(A0, B1, acc01, 4, 4, 0, SC, 0, SC); \
        acc10 = __builtin_amdgcn_mfma_scale_f32_32x32x64_f8f6f4(A1, B0, acc10, 4, 4, 0, SC, 0, SC); \
        acc11 = __builtin_amdgcn_mfma_scale_f32_32x32x64_f8f6f4(A1, B1, acc11, 4, 4, 0, SC, 0, SC); \
    }

#define TAPCOMPUTE(USE, IT)                                                                \
    {                                                                                      \
        const int pL0 = po0 + ((IT) / 3) * 58 + ((IT) % 3);                                \
        const int pL1 = po1 + ((IT) / 3) * 58 + ((IT) % 3);                                \
        const int8_t* a0b = sX + pL0 * 128;                                                \
        const int8_t* a1b = sX + pL1 * 128;                                                \
        const int xx0 = (pL0 & 7) << 4;                                                    \
        const int xx1 = (pL1 & 7) << 4;                                                    \
        __builtin_amdgcn_s_setprio(1);                                                     \
        MFMA_KK(0, USE##_0, USE##_4)  MFMA_KK(1, USE##_1, USE##_5)                         \
        MFMA_KK(2, USE##_2, USE##_6)  MFMA_KK(3, USE##_3, USE##_7)                         \
        __builtin_amdgcn_s_setprio(0);                                                     \
    }
#define SBAR __builtin_amdgcn_sched_barrier(0);

    LOADSET(bA, 0)
    __syncthreads();   // vmcnt(0)+barrier: A window staged by all waves; only barrier in kernel

    // 9 taps, depth-1 prefetch, sched_barrier fences the hoisting window to one tap
    LOADSET(bC, 1)  TAPCOMPUTE(bA, 0)  SBAR
    LOADSET(bA, 2)  TAPCOMPUTE(bC, 1)  SBAR
    LOADSET(bC, 3)  TAPCOMPUTE(bA, 2)  SBAR
    LOADSET(bA, 4)  TAPCOMPUTE(bC, 3)  SBAR
    LOADSET(bC, 5)  TAPCOMPUTE(bA, 4)  SBAR
    LOADSET(bA, 6)  TAPCOMPUTE(bC, 5)  SBAR
    LOADSET(bC, 7)  TAPCOMPUTE(bA, 6)  SBAR
    LOADSET(bA, 8)  TAPCOMPUTE(bC, 7)  SBAR
    TAPCOMPUTE(bA, 8)

#undef SBAR
#undef TAPCOMPUTE
#undef MFMA_KK
#undef LOADSET

    // epilogue: 32x32 C/D layout col=lane&31, row=(reg&3)+8*(reg>>2)+4*(lane>>5); out = acc/9
    // literal-index macros: no runtime vector subscripts anywhere. pad rows (>=3136) masked.
    const float s = 1.0f / 9.0f;
    const long outImg = (long)n * 3136;

#define ST1(ACC, MT, REG)                                                                  \
    {                                                                                      \
        const int row = ((REG) & 3) + 8 * ((REG) >> 2) + 4 * hi;                           \
        const int rowLocal = m0 + wm + (MT) * 32 + row;                                    \
        if (rowLocal < 3136)                                                               \
            out[(outImg + rowLocal) * 256 + ocol] = ACC[REG] * s;                          \
    }
#define ST_ALL(ACC, MT, NT)                                                                \
    {                                                                                      \
        const int ocol = coBase + wn + (NT) * 32 + l31;                                    \
        ST1(ACC, MT, 0)  ST1(ACC, MT, 1)  ST1(ACC, MT, 2)  ST1(ACC, MT, 3)                 \
        ST1(ACC, MT, 4)  ST1(ACC, MT, 5)  ST1(ACC, MT, 6)  ST1(ACC, MT, 7)                 \
        ST1(ACC, MT, 8)  ST1(ACC, MT, 9)  ST1(ACC, MT, 10) ST1(ACC, MT, 11)                \
        ST1(ACC, MT, 12) ST1(ACC, MT, 13) ST1(ACC, MT, 14) ST1(ACC, MT, 15)                \
    }

    ST_ALL(acc00, 0, 0)
    ST_ALL(acc01, 0, 1)
    ST_ALL(acc10, 1, 0)
    ST_ALL(acc11, 1, 1)
#undef ST_ALL
#undef ST1
}

extern "C" void kernel_launch(void* const* d_in, const int* in_sizes, int n_in,
                              void* d_out, int out_size, void* d_ws, size_t ws_size,
                              hipStream_t stream) {
    const float* x = (const float*)d_in[0];   // (32,56,56,256) NHWC fp32
    const float* w = (const float*)d_in[1];   // (3,3,256,256) HWIO fp32
    float* out = (float*)d_out;               // (32,56,56,256) fp32

    unsigned* maxbits = (unsigned*)d_ws;
    int8_t* wqt = (int8_t*)d_ws + 4096;              // 256*1152 = 294912 B, [co][k/2]
    int8_t* xqp = (int8_t*)d_ws + 4096 + 294912;     // 32*58*58*128 = 13,778,944 B

    hipMemsetAsync(maxbits, 0, 4, stream);           // ws poisoned 0xAA -> zero for atomicMax
    k_xq_wmax<<<48 + 3364, 256, 0, stream>>>(x, w, xqp, maxbits);  // wmax hides under xq
    k_wq<<<72, 256, 0, stream>>>(w, maxbits, wqt);
    k_conv<<<1600, 256, 0, stream>>>(xqp, wqt, out);  // 32 images x 25 tiles x 2 co-halves
}

// Round 12
// 229.946 us; speedup vs baseline: 1.2438x; 1.2438x over previous
//
#include <hip/hip_runtime.h>
#include <stdint.h>

#define GLOBAL_AS __attribute__((address_space(1)))
#define LDS_AS    __attribute__((address_space(3)))

typedef int   v4i  __attribute__((ext_vector_type(4)));
typedef int   v8i  __attribute__((ext_vector_type(8)));
typedef float v16f __attribute__((ext_vector_type(16)));

__device__ __forceinline__ void gload_lds16(const void* g, void* l) {
    __builtin_amdgcn_global_load_lds((GLOBAL_AS uint32_t*)g, (LDS_AS uint32_t*)l, 16, 0, 0);
}

// fp4 e2m1 encodings: {0,1,2,3} -> {0x0,0x2,0x4,0x5}; {-3,-1,1,3} -> {0xD,0xA,0x2,0x5}
//   act   nibble = (0x5420 >> (q*4)) & 0xF
//   wght  nibble = (0x52AD >> (q*4)) & 0xF   (q = 0..3 maps to -3,-1,1,3)

// ---------------- kernel 1 (fused): weight-max (blocks 0..47) + act quantize -> fp4 ----------
__global__ void k_xq_wmax(const float* __restrict__ x, const float* __restrict__ w,
                          int8_t* __restrict__ xqp, unsigned* __restrict__ maxbits) {
    const int bid = blockIdx.x;
    if (bid < 48) {
        int t = bid * 256 + threadIdx.x;
        const float4* w4 = (const float4*)w;
        float m = 0.f;
        for (int i = t; i < 147456; i += 12288) {
            float4 v = w4[i];
            m = fmaxf(m, fmaxf(fmaxf(fabsf(tanhf(v.x)), fabsf(tanhf(v.y))),
                               fmaxf(fabsf(tanhf(v.z)), fabsf(tanhf(v.w)))));
        }
#pragma unroll
        for (int off = 32; off > 0; off >>= 1)
            m = fmaxf(m, __shfl_xor(m, off, 64));
        if ((threadIdx.x & 63) == 0) atomicMax(maxbits, __float_as_uint(m));
        return;
    }
    int t = (bid - 48) * 256 + threadIdx.x;   // 32*58*58*8 threads, 16 bytes (32 ch) each
    int g  = t & 7;
    int p  = t >> 3;
    int xp = p % 58;
    int q  = p / 58;
    int yp = q % 58;
    int n  = q / 58;
    int4 r;
    if (yp == 0 || yp == 57 || xp == 0 || xp == 57) {
        r = make_int4(0, 0, 0, 0);
    } else {
        const float4* px = (const float4*)(x + (((long)((n * 56 + (yp - 1)) * 56 + (xp - 1))) << 8) + g * 32);
        int wds[4];
#pragma unroll
        for (int jj = 0; jj < 4; ++jj) {
            float4 v0 = px[jj * 2];
            float4 v1 = px[jj * 2 + 1];
            int q0 = (int)rintf(fminf(fmaxf(v0.x, 0.f), 1.f) * 3.f);
            int q1 = (int)rintf(fminf(fmaxf(v0.y, 0.f), 1.f) * 3.f);
            int q2 = (int)rintf(fminf(fmaxf(v0.z, 0.f), 1.f) * 3.f);
            int q3 = (int)rintf(fminf(fmaxf(v0.w, 0.f), 1.f) * 3.f);
            int q4 = (int)rintf(fminf(fmaxf(v1.x, 0.f), 1.f) * 3.f);
            int q5 = (int)rintf(fminf(fmaxf(v1.y, 0.f), 1.f) * 3.f);
            int q6 = (int)rintf(fminf(fmaxf(v1.z, 0.f), 1.f) * 3.f);
            int q7 = (int)rintf(fminf(fmaxf(v1.w, 0.f), 1.f) * 3.f);
            wds[jj] = ((0x5420 >> (q0 << 2)) & 0xF)        | (((0x5420 >> (q1 << 2)) & 0xF) << 4)
                    | (((0x5420 >> (q2 << 2)) & 0xF) << 8) | (((0x5420 >> (q3 << 2)) & 0xF) << 12)
                    | (((0x5420 >> (q4 << 2)) & 0xF) << 16)| (((0x5420 >> (q5 << 2)) & 0xF) << 20)
                    | (((0x5420 >> (q6 << 2)) & 0xF) << 24)| (((0x5420 >> (q7 << 2)) & 0xF) << 28);
        }
        r = make_int4(wds[0], wds[1], wds[2], wds[3]);
    }
    *(int4*)(xqp + ((long)t << 4)) = r;
}

// ---------------- kernel 2: quantize weights -> fp4 {-3,-1,1,3}, layout [co][tap*128+ci/2] ---
__global__ void k_wq(const float* __restrict__ w, const unsigned* __restrict__ maxbits,
                     int8_t* __restrict__ wqt) {
    int t = blockIdx.x * 256 + threadIdx.x;   // 18432 threads
    int co = t & 255;
    int kblk = t >> 8;                        // 0..71, 32 k-values each
    float inv = 0.5f / __uint_as_float(*maxbits);
    uint8_t b[16];
#pragma unroll
    for (int j = 0; j < 16; ++j) {
        float t0 = tanhf(w[(long)(kblk * 32 + 2 * j) * 256 + co]);     // HWIO [k][co]
        float t1 = tanhf(w[(long)(kblk * 32 + 2 * j + 1) * 256 + co]);
        int q0 = (int)rintf((t0 * inv + 0.5f) * 3.0f);                 // 0..3, half-even
        int q1 = (int)rintf((t1 * inv + 0.5f) * 3.0f);
        b[j] = (uint8_t)(((0x52AD >> (q0 << 2)) & 0xF) | (((0x52AD >> (q1 << 2)) & 0xF) << 4));
    }
    *(int4*)(wqt + (long)co * 1152 + kblk * 16) = *(int4*)b;
}

// ---------------- kernel 3: two-phase implicit-GEMM conv, MX-fp4 MFMA 32x32x64 --------------
// Hybrid of the two proven designs (R3 pipeline + R10-verified A-window addressing):
//  - A-window (256 px x 128 B = 32 KB) staged to LDS ONCE; all 9 taps index into it.
//  - B: one 16 KB tap-tile per iter, LDS double-buffered, R3's vmcnt(4)+s_barrier pipeline
//    (prefetch tap it+1 stays in flight across the barrier while tap it computes).
// Round-10/11 lesson: the barrier-free all-register-B design intrinsically needs ~256 VGPR
// (8-reg zero-extended mfma_scale operand tuples) -> 1 wave/SIMD. The 2-phase barrier
// structure bounds transient tuple pressure (R1/R3: ~88 VGPR) at the cost of 2 barriers/tap.
#define BM 128
#define BN 128

__global__ __launch_bounds__(256) void k_conv(const int8_t* __restrict__ xqp,
                                              const int8_t* __restrict__ wqt,
                                              float* __restrict__ out) {
    __shared__ int8_t sX[256 * 128];        // 32 KB A window, staged once
    __shared__ int8_t sB[2][128 * 128];     // 2 x 16 KB B tap double-buffer

    const int tid  = threadIdx.x;
    const int wv   = tid >> 6;
    const int lane = tid & 63;
    const int orig = blockIdx.x;                   // 1600 blocks, %8==0 -> bijective swizzle
    const int work = (orig & 7) * 200 + (orig >> 3);
    const int coBase = (work & 1) << 7;
    const int wt   = work >> 1;                    // 0..799
    const int n    = wt / 25;
    const int t    = wt - n * 25;

    const int m0 = t * 128;                        // local row base within image n
    const int y0 = m0 / 56;
    const int x0 = m0 - y0 * 56;
    const long pixBase = ((long)(n * 58 + y0)) * 58 + x0;  // padded pixel of tap(0,0), row 0

    const int lr = lane >> 3;
    const int lp = lane & 7;

    // ---- stage A window: 256 pixels x 128B, chunk-swizzled (g = lp ^ (p&7)), once ----
#pragma unroll
    for (int j = 0; j < 8; ++j) {
        int p = wv * 8 + j * 32 + lr;              // 0..255
        int g = lp ^ (p & 7);
        long pg = pixBase + p;
        if (pg > 107647) pg = 107647;              // clamp inside xqp (32*58*58 pixels)
        gload_lds16(xqp + (pg << 7) + g * 16, &sX[(wv * 8 + j * 32) * 128]);
    }

    // ---- B staging bases: instruction (wv,j) covers rows rbase..rbase+7, 4 loads/thread ----
    const int8_t* bB[4];
#pragma unroll
    for (int j = 0; j < 4; ++j) {
        int r = wv * 8 + j * 32 + lr;              // 0..127
        int g = lp ^ (r & 7);
        bB[j] = wqt + (long)(coBase + r) * 1152 + g * 16;
    }

    const int wm  = (wv & 1) * 64;
    const int wn  = (wv >> 1) * 64;
    const int l31 = lane & 31;
    const int hi  = lane >> 5;
    const int h16 = hi << 4;

    // per-thread A-row pixel offsets (relative to pixBase); pad rows clamp to m=3135
    int mL0 = m0 + wm + l31;      if (mL0 > 3135) mL0 = 3135;
    int mL1 = m0 + wm + 32 + l31; if (mL1 > 3135) mL1 = 3135;
    const int yR0 = mL0 / 56, xR0 = mL0 - yR0 * 56;
    const int yR1 = mL1 / 56, xR1 = mL1 - yR1 * 56;
    const int po0 = (yR0 - y0) * 58 + (xR0 - x0);   // <= 133
    const int po1 = (yR1 - y0) * 58 + (xR1 - x0);

    // B fragment row offsets in the tap tile + XOR terms (rows are co-columns wn.., wn+32..)
    const int rB0 = (wn + l31) * 128;       const int bxr0 = ((wn + l31) & 7) << 4;
    const int rB1 = (wn + 32 + l31) * 128;  const int bxr1 = ((wn + 32 + l31) & 7) << 4;

    v16f acc00 = {0,0,0,0,0,0,0,0,0,0,0,0,0,0,0,0};
    v16f acc01 = {0,0,0,0,0,0,0,0,0,0,0,0,0,0,0,0};
    v16f acc10 = {0,0,0,0,0,0,0,0,0,0,0,0,0,0,0,0};
    v16f acc11 = {0,0,0,0,0,0,0,0,0,0,0,0,0,0,0,0};

    const int SC = 0x7F7F7F7F;                      // e8m0 127 -> scale 1.0

    auto issueB = [&](int it, int b) {              // 4 x gload_lds16: one 16 KB tap tile
#pragma unroll
        for (int j = 0; j < 4; ++j)
            gload_lds16(bB[j] + it * 128, &sB[b][(wv * 8 + j * 32) * 128]);
    };

    auto compute = [&](int it, int b) {
        const int tapoff = (it / 3) * 58 + (it % 3);
        const int pL0 = po0 + tapoff;
        const int pL1 = po1 + tapoff;
        const int8_t* a0b = sX + pL0 * 128;
        const int8_t* a1b = sX + pL1 * 128;
        const int xx0 = (pL0 & 7) << 4;
        const int xx1 = (pL1 & 7) << 4;
        const int8_t* pB = sB[b];
        __builtin_amdgcn_s_setprio(1);
#pragma unroll
        for (int kk = 0; kk < 4; ++kk) {
            const int kc = kk * 32 + h16;
            v4i a0 = *(const v4i*)(a0b + (kc ^ xx0));
            v4i a1 = *(const v4i*)(a1b + (kc ^ xx1));
            v4i b0 = *(const v4i*)(pB + rB0 + (kc ^ bxr0));
            v4i b1 = *(const v4i*)(pB + rB1 + (kc ^ bxr1));
            v8i A0 = {a0[0], a0[1], a0[2], a0[3], 0, 0, 0, 0};
            v8i A1 = {a1[0], a1[1], a1[2], a1[3], 0, 0, 0, 0};
            v8i B0 = {b0[0], b0[1], b0[2], b0[3], 0, 0, 0, 0};
            v8i B1 = {b1[0], b1[1], b1[2], b1[3], 0, 0, 0, 0};
            acc00 = __builtin_amdgcn_mfma_scale_f32_32x32x64_f8f6f4(A0, B0, acc00, 4, 4, 0, SC, 0, SC);
            acc01 = __builtin_amdgcn_mfma_scale_f32_32x32x64_f8f6f4(A0, B1, acc01, 4, 4, 0, SC, 0, SC);
            acc10 = __builtin_amdgcn_mfma_scale_f32_32x32x64_f8f6f4(A1, B0, acc10, 4, 4, 0, SC, 0, SC);
            acc11 = __builtin_amdgcn_mfma_scale_f32_32x32x64_f8f6f4(A1, B1, acc11, 4, 4, 0, SC, 0, SC);
        }
        __builtin_amdgcn_s_setprio(0);
    };

    // -------- pipelined tap loop: 9 taps, depth-1 B prefetch (R3's proven schedule) --------
    issueB(0, 0);
#pragma unroll 2
    for (int it = 0; it < 8; ++it) {
        issueB(it + 1, (it + 1) & 1);                    // prefetch next tap (4 loads in flight)
        // first iter: outstanding = A(8) + B0(4) + B1(4) = 16 -> vmcnt(4) drains A and B0,
        // leaves B1's 4 in flight across the barrier. steady state: drains B(it) only.
        asm volatile("s_waitcnt vmcnt(4)" ::: "memory");
        __builtin_amdgcn_s_barrier();
        asm volatile("" ::: "memory");
        compute(it, it & 1);
        asm volatile("" ::: "memory");                   // all waves done reading buf before overwrite
        __builtin_amdgcn_s_barrier();
        asm volatile("" ::: "memory");
    }
    asm volatile("s_waitcnt vmcnt(0)" ::: "memory");     // drain tap 8's loads
    __builtin_amdgcn_s_barrier();
    asm volatile("" ::: "memory");
    compute(8, 0);                                       // tap 8 -> buf 0

    // epilogue: 32x32 C/D layout col=lane&31, row=(reg&3)+8*(reg>>2)+4*(lane>>5); out = acc/9
    // literal-index macros; pad-tile rows (>=3136) masked.
    const float s = 1.0f / 9.0f;
    const long outImg = (long)n * 3136;

#define ST1(ACC, MT, REG)                                                                  \
    {                                                                                      \
        const int row = ((REG) & 3) + 8 * ((REG) >> 2) + 4 * hi;                           \
        const int rowLocal = m0 + wm + (MT) * 32 + row;                                    \
        if (rowLocal < 3136)                                                               \
            out[(outImg + rowLocal) * 256 + ocol] = ACC[REG] * s;                          \
    }
#define ST_ALL(ACC, MT, NT)                                                                \
    {                                                                                      \
        const int ocol = coBase + wn + (NT) * 32 + l31;                                    \
        ST1(ACC, MT, 0)  ST1(ACC, MT, 1)  ST1(ACC, MT, 2)  ST1(ACC, MT, 3)                 \
        ST1(ACC, MT, 4)  ST1(ACC, MT, 5)  ST1(ACC, MT, 6)  ST1(ACC, MT, 7)                 \
        ST1(ACC, MT, 8)  ST1(ACC, MT, 9)  ST1(ACC, MT, 10) ST1(ACC, MT, 11)                \
        ST1(ACC, MT, 12) ST1(ACC, MT, 13) ST1(ACC, MT, 14) ST1(ACC, MT, 15)                \
    }

    ST_ALL(acc00, 0, 0)
    ST_ALL(acc01, 0, 1)
    ST_ALL(acc10, 1, 0)
    ST_ALL(acc11, 1, 1)
#undef ST_ALL
#undef ST1
}

extern "C" void kernel_launch(void* const* d_in, const int* in_sizes, int n_in,
                              void* d_out, int out_size, void* d_ws, size_t ws_size,
                              hipStream_t stream) {
    const float* x = (const float*)d_in[0];   // (32,56,56,256) NHWC fp32
    const float* w = (const float*)d_in[1];   // (3,3,256,256) HWIO fp32
    float* out = (float*)d_out;               // (32,56,56,256) fp32

    unsigned* maxbits = (unsigned*)d_ws;
    int8_t* wqt = (int8_t*)d_ws + 4096;              // 256*1152 = 294912 B, [co][k/2]
    int8_t* xqp = (int8_t*)d_ws + 4096 + 294912;     // 32*58*58*128 = 13,778,944 B

    hipMemsetAsync(maxbits, 0, 4, stream);           // ws poisoned 0xAA -> zero for atomicMax
    k_xq_wmax<<<48 + 3364, 256, 0, stream>>>(x, w, xqp, maxbits);  // wmax hides under xq
    k_wq<<<72, 256, 0, stream>>>(w, maxbits, wqt);
    k_conv<<<1600, 256, 0, stream>>>(xqp, wqt, out);  // 32 images x 25 tiles x 2 co-halves
}